// Round 3
// baseline (297.520 us; speedup 1.0000x reference)
//
#include <hip/hip_runtime.h>

// DualModel3 R3: fc head + 4096 decoder MLPs, one bf16-MFMA GEMM kernel.
// R2 lesson: occupancy fix alone didn't help (MfmaUtil 5%, VALU 7%) — the
// 1-deep prefetch exposes ~500cyc load latency every iter. R3: 2-deep
// register pipeline (tile k+3 issued while k+1 staged; plain register loads
// so __syncthreads drains lgkmcnt only, loads stay in flight), B staging
// via dwordx4 (4 VMEM instead of 16), 2x2 wave tiling (less LDS frag BW).
//
// Grid: (16 fc + 256 dec) col-groups x 4 row-groups = 1088 blocks x 256 thr.
// BM=64, BN=64, BK=64, mfma_f32_16x16x32_bf16.
// C/D layout col=lane&15, row=quad*4+reg (m89). Decoder epilogue: bias +
// leaky-relu + W2-weighted H-reduction via __shfl_xor over 4 adjacent lanes.

typedef __bf16 bf16_t;
typedef __bf16 bf16x8 __attribute__((ext_vector_type(8)));
typedef __bf16 bf16x4 __attribute__((ext_vector_type(4)));
typedef float  f32x4  __attribute__((ext_vector_type(4)));

#define LDSTR 72          // bf16/row: 64 + 8 pad
#define ROWB  (LDSTR*2)   // 144 B row stride

__global__ __launch_bounds__(256, 4)
void fused_dual(const float* __restrict__ x,    // [256,2048]
                const float* __restrict__ fcW,  // [1000,2048]
                const float* __restrict__ fcb,  // [1000]
                const float* __restrict__ W1,   // [4096,2048,4]
                const float* __restrict__ b1,   // [4096,4]
                const float* __restrict__ W2,   // [4096,4]
                const float* __restrict__ b2,   // [4096]
                float* __restrict__ out)        // x1[256*1000] ++ x2[256*4096]
{
    __shared__ bf16_t lA[64 * LDSTR];   // 9216 B
    __shared__ bf16_t lB[64 * LDSTR];   // 9216 B
    char* lAb = (char*)lA;
    char* lBb = (char*)lB;

    const int tid = threadIdx.x, blk = blockIdx.x;
    const int cg = blk >> 2, rg = blk & 3, m0 = rg * 64;
    const bool is_fc = (cg < 16);
    const int c0 = (is_fc ? cg : cg - 16) * 64;

    // A: thread -> row tid>>2, k-group tid&3 (16 consecutive floats)
    const float* aBase = x + (m0 + (tid >> 2)) * 2048 + (tid & 3) * 16;
    const int aW = (tid >> 2) * ROWB + (tid & 3) * 32;

    // B: fc -> row tid>>2, 16 consecutive k.  decoder -> o tid>>4, 16 floats
    // = W1[o][k0..k0+3][h0..3] (64B contiguous per lane).
    const float* bBase;
    int bStride, bW;
    if (is_fc) {
        int row = c0 + (tid >> 2); if (row > 999) row = 999;  // stores guarded
        bBase = fcW + row * 2048 + (tid & 3) * 16;
        bStride = 64;
        bW = (tid >> 2) * ROWB + (tid & 3) * 32;
    } else {
        bBase = W1 + ((c0 >> 2) + (tid >> 4)) * 8192 + (tid & 15) * 16;
        bStride = 256;
        bW = (tid >> 4) * 4 * ROWB + (tid & 15) * 8;
    }

    f32x4 aR0[4], bR0[4], aR1[4], bR1[4];

#define ISSUE(AR, BR, TL) do {                                              \
    const float* _a = aBase + (TL) * 64;                                    \
    const float* _b = bBase + (TL) * bStride;                               \
    _Pragma("unroll") for (int q = 0; q < 4; ++q) AR[q] = *(const f32x4*)(_a + q * 4); \
    _Pragma("unroll") for (int q = 0; q < 4; ++q) BR[q] = *(const f32x4*)(_b + q * 4); \
} while (0)

    // cvt fp32->bf16 and write LDS. A: 2 x b128. B fc: 2 x b128.
    // B decoder: transpose pack -> 4 x b64 (row o*4+h, k0..k0+3).
#define STAGE(AR, BR) do {                                                  \
    bf16x8 _va0, _va1;                                                      \
    _Pragma("unroll") for (int c = 0; c < 4; ++c) {                         \
        _va0[c] = (bf16_t)AR[0][c]; _va0[4 + c] = (bf16_t)AR[1][c];         \
        _va1[c] = (bf16_t)AR[2][c]; _va1[4 + c] = (bf16_t)AR[3][c]; }       \
    *(bf16x8*)(lAb + aW) = _va0; *(bf16x8*)(lAb + aW + 16) = _va1;          \
    if (is_fc) {                                                            \
        bf16x8 _vb0, _vb1;                                                  \
        _Pragma("unroll") for (int c = 0; c < 4; ++c) {                     \
            _vb0[c] = (bf16_t)BR[0][c]; _vb0[4 + c] = (bf16_t)BR[1][c];     \
            _vb1[c] = (bf16_t)BR[2][c]; _vb1[4 + c] = (bf16_t)BR[3][c]; }   \
        *(bf16x8*)(lBb + bW) = _vb0; *(bf16x8*)(lBb + bW + 16) = _vb1;      \
    } else {                                                                \
        _Pragma("unroll") for (int h = 0; h < 4; ++h) {                     \
            bf16x4 _v;                                                      \
            _Pragma("unroll") for (int q = 0; q < 4; ++q) _v[q] = (bf16_t)BR[q][h]; \
            *(bf16x4*)(lBb + bW + h * ROWB) = _v; }                         \
    }                                                                       \
} while (0)

    const int lane = tid & 63, wav = tid >> 6, l15 = lane & 15, quad = lane >> 4;
    const int mt0 = (wav & 1) * 2, nt0 = (wav >> 1) * 2;  // 2x2 wave tiling

    f32x4 acc[2][2];
    acc[0][0] = acc[0][1] = acc[1][0] = acc[1][1] = (f32x4){0.f, 0.f, 0.f, 0.f};
    bf16x8 af[2][2], bfr[2][2];

#define FRAGS() do {                                                        \
    _Pragma("unroll") for (int kk = 0; kk < 2; ++kk)                        \
    _Pragma("unroll") for (int i = 0; i < 2; ++i) {                         \
        af[kk][i]  = *(const bf16x8*)(lAb + ((mt0 + i) * 16 + l15) * ROWB + kk * 64 + quad * 16); \
        bfr[kk][i] = *(const bf16x8*)(lBb + ((nt0 + i) * 16 + l15) * ROWB + kk * 64 + quad * 16); \
    }                                                                       \
} while (0)

#define MFMA8() do {                                                        \
    _Pragma("unroll") for (int kk = 0; kk < 2; ++kk)                        \
    _Pragma("unroll") for (int i = 0; i < 2; ++i)                           \
    _Pragma("unroll") for (int j = 0; j < 2; ++j)                           \
        acc[i][j] = __builtin_amdgcn_mfma_f32_16x16x32_bf16(af[kk][i], bfr[kk][j], acc[i][j], 0, 0, 0); \
} while (0)

    // ---- prologue: tiles 0,1 issued; tile 0 staged; tile 2 issued ----
    ISSUE(aR0, bR0, 0);
    ISSUE(aR1, bR1, 1);
    STAGE(aR0, bR0);
    ISSUE(aR0, bR0, 2);
    __syncthreads();

    // invariant entering iter kt: LDS = tile kt; odd-reg set holds kt+1(ish);
    // tile t lives in regset (t&1). Loads consumed 2 iters after issue.
    for (int kt = 0; kt < 32; kt += 2) {
        // ---- even iter kt ----
        FRAGS();                       // tile kt
        __syncthreads();               // frag reads done before overwrite
        STAGE(aR1, bR1);               // tile kt+1 (regs loaded 2 iters ago)
        if (kt + 3 < 32) ISSUE(aR1, bR1, kt + 3);
        __syncthreads();               // tile kt+1 visible
        MFMA8();
        // ---- odd iter kt+1 ----
        FRAGS();                       // tile kt+1
        __syncthreads();
        if (kt + 1 < 31) {
            STAGE(aR0, bR0);           // tile kt+2
            if (kt + 4 < 32) ISSUE(aR0, bR0, kt + 4);
            __syncthreads();
        }
        MFMA8();
    }

    // ---- epilogue ----
    if (is_fc) {
        #pragma unroll
        for (int j = 0; j < 2; ++j) {
            const int c = c0 + (nt0 + j) * 16 + l15;
            const bool valid = (c < 1000);
            const float bias = fcb[valid ? c : 999];
            #pragma unroll
            for (int i = 0; i < 2; ++i)
            #pragma unroll
            for (int r = 0; r < 4; ++r)
                if (valid) {
                    const int row = m0 + (mt0 + i) * 16 + quad * 4 + r;
                    out[row * 1000 + c] = acc[i][j][r] + bias;
                }
        }
    } else {
        float* x2 = out + 256 * 1000;
        #pragma unroll
        for (int j = 0; j < 2; ++j) {
            const int c = c0 + (nt0 + j) * 16 + l15;   // [0,16384)
            const float b1v = b1[c], w2v = W2[c];
            const int o = c >> 2;
            const float b2v = b2[o];
            #pragma unroll
            for (int i = 0; i < 2; ++i)
            #pragma unroll
            for (int r = 0; r < 4; ++r) {
                float h = acc[i][j][r] + b1v;
                h = (h >= 0.f) ? h : 0.1f * h;         // leaky relu
                float wv = h * w2v;
                wv += __shfl_xor(wv, 1, 64);           // sum 4 h-cols of decoder
                wv += __shfl_xor(wv, 2, 64);
                if ((lane & 3) == 0) {
                    const int row = m0 + (mt0 + i) * 16 + quad * 4 + r;
                    x2[row * 4096 + o] = wv + b2v;
                }
            }
        }
    }
}

extern "C" void kernel_launch(void* const* d_in, const int* in_sizes, int n_in,
                              void* d_out, int out_size, void* d_ws, size_t ws_size,
                              hipStream_t stream)
{
    (void)in_sizes; (void)n_in; (void)d_ws; (void)ws_size; (void)out_size;
    const float* x   = (const float*)d_in[0];
    const float* fcW = (const float*)d_in[1];
    const float* fcb = (const float*)d_in[2];
    const float* W1  = (const float*)d_in[3];
    const float* b1  = (const float*)d_in[4];
    const float* W2  = (const float*)d_in[5];
    const float* b2  = (const float*)d_in[6];
    fused_dual<<<1088, 256, 0, stream>>>(x, fcW, fcb, W1, b1, W2, b2, (float*)d_out);
}